// Round 10
// baseline (467.432 us; speedup 1.0000x reference)
//
#include <hip/hip_runtime.h>

typedef unsigned short u16;
typedef unsigned char u8;
typedef unsigned int u32;
typedef float f32x4 __attribute__((ext_vector_type(4)));
typedef __bf16 bf16x8 __attribute__((ext_vector_type(8)));
typedef int i32x4 __attribute__((ext_vector_type(4)));
typedef int i32x8 __attribute__((ext_vector_type(8)));

// ---------- bf16 helpers (RNE) ----------
__device__ __forceinline__ u16 f2bf(float f) {
    unsigned u = __float_as_uint(f);
    u += 0x7FFFu + ((u >> 16) & 1u);
    return (u16)(u >> 16);
}
__device__ __forceinline__ float b2f(u16 h) {
    return __uint_as_float(((unsigned)h) << 16);
}

// ---------- async global->LDS, 16B per lane, wave-uniform LDS base ----------
__device__ __forceinline__ void async16(const void* g, void* l) {
    __builtin_amdgcn_global_load_lds(
        (__attribute__((address_space(1))) void*)g,
        (__attribute__((address_space(3))) void*)l,
        16, 0, 0);
}

#define T_TOK 4096
#define DIM   2048

__device__ __forceinline__ void cast4f(const float* __restrict__ s,
                                       u16* __restrict__ d, int j) {
    float4 f = ((const float4*)s)[j];
    ushort4 u;
    u.x = f2bf(f.x); u.y = f2bf(f.y); u.z = f2bf(f.z); u.w = f2bf(f.w);
    ((ushort4*)d)[j] = u;
}

// ---------- kernel 1: W_in cast (0..8191) + LN (8192..12287) — round-7 proven ----------
__global__ __launch_bounds__(256) void castln_kernel(const float* __restrict__ W_in,
                                                     u16* __restrict__ wb_in,
                                                     const float* __restrict__ x,
                                                     const float* __restrict__ g,
                                                     const float* __restrict__ b,
                                                     u16* __restrict__ xnb) {
    __shared__ float s1[4], s2[4];
    int blk = blockIdx.x, tid = threadIdx.x;
    if (blk < 8192) { cast4f(W_in, wb_in, blk * 256 + tid); return; }
    int t = blk - 8192;
    int wave = tid >> 6, lane = tid & 63;
    size_t base = (size_t)t * DIM;
    int d0 = tid * 8;
    float4 v0 = *(const float4*)(x + base + d0);
    float4 v1 = *(const float4*)(x + base + d0 + 4);
    float v[8] = {v0.x, v0.y, v0.z, v0.w, v1.x, v1.y, v1.z, v1.w};
    float s = 0.f;
#pragma unroll
    for (int j = 0; j < 8; ++j) s += v[j];
#pragma unroll
    for (int o2 = 32; o2; o2 >>= 1) s += __shfl_xor(s, o2);
    if (lane == 0) s1[wave] = s;
    __syncthreads();
    float mu = (s1[0] + s1[1] + s1[2] + s1[3]) * (1.f / DIM);
    float q = 0.f;
#pragma unroll
    for (int j = 0; j < 8; ++j) { float dd = v[j] - mu; q += dd * dd; }
#pragma unroll
    for (int o2 = 32; o2; o2 >>= 1) q += __shfl_xor(q, o2);
    if (lane == 0) s2[wave] = q;
    __syncthreads();
    float var = (s2[0] + s2[1] + s2[2] + s2[3]) * (1.f / DIM);
    float rs = rsqrtf(var + 1e-5f);
    float4 g0 = *(const float4*)(g + d0), g1 = *(const float4*)(g + d0 + 4);
    float4 b0 = *(const float4*)(b + d0), b1 = *(const float4*)(b + d0 + 4);
    float gv[8] = {g0.x, g0.y, g0.z, g0.w, g1.x, g1.y, g1.z, g1.w};
    float bv[8] = {b0.x, b0.y, b0.z, b0.w, b1.x, b1.y, b1.z, b1.w};
    ushort4 r0, r1;
    u16* rp0 = (u16*)&r0; u16* rp1 = (u16*)&r1;
#pragma unroll
    for (int j = 0; j < 4; ++j) {
        rp0[j] = f2bf((v[j] - mu) * rs * gv[j] + bv[j]);
        rp1[j] = f2bf((v[j + 4] - mu) * rs * gv[j + 4] + bv[j + 4]);
    }
    *(ushort4*)(xnb + base + d0) = r0;
    *(ushort4*)(xnb + base + d0 + 4) = r1;
}

// ---------- kernel 2: wide GEMM 128x128, BK=64, XOR-swizzled (round-7 proven) ----------
#define WBM 128
#define WBN 128
#define WBK 64

__global__ __launch_bounds__(256) void gemm_wide(const u16* __restrict__ A,
                                                 const u16* __restrict__ W,
                                                 const float* __restrict__ bias,
                                                 u16* __restrict__ Xs,
                                                 u16* __restrict__ Z, int K) {
    __shared__ __align__(16) u16 lAB[(WBM + WBN) * WBK];  // 32 KB
    const int tid = threadIdx.x;
    const int wave = tid >> 6, lane = tid & 63;
    const int quad = lane >> 4, l16 = lane & 15;
    const int tM = blockIdx.x * WBM;
    const int tN = blockIdx.y * WBN;
    const int wr = wave >> 1, wc = wave & 1;

    const int rowin = tid >> 3;
    const int col8 = ((tid & 7) ^ (rowin & 7)) * 8;
    const u16* gptr[8];
    u16* ldst[8];
#pragma unroll
    for (int i = 0; i < 8; ++i) {
        int trow = i * 32 + rowin;
        const u16* src = (i < 4) ? (A + (size_t)(tM + trow) * 2048)
                                 : (W + (size_t)(tN + (trow - WBM)) * 2048);
        gptr[i] = src + col8;
        ldst[i] = &lAB[(i * 32 + wave * 8) * WBK];
    }

    int a_off[2][4], b_off[2][4];
#pragma unroll
    for (int h = 0; h < 2; ++h) {
#pragma unroll
        for (int mi = 0; mi < 4; ++mi)
            a_off[h][mi] = (wr * 64 + mi * 16 + l16) * WBK +
                           (((h * 4 + quad) ^ (l16 & 7)) * 8);
#pragma unroll
        for (int ni = 0; ni < 4; ++ni)
            b_off[h][ni] = (WBM + wc * 64 + ni * 16 + l16) * WBK +
                           (((h * 4 + quad) ^ (l16 & 7)) * 8);
    }

    f32x4 acc[4][4] = {};

    for (int kt = 0; kt < K; kt += WBK) {
#pragma unroll
        for (int i = 0; i < 8; ++i) async16(gptr[i] + kt, ldst[i]);
        __syncthreads();
#pragma unroll
        for (int h = 0; h < 2; ++h) {
            bf16x8 af[4], bfr[4];
#pragma unroll
            for (int i = 0; i < 4; ++i) af[i] = *(const bf16x8*)&lAB[a_off[h][i]];
#pragma unroll
            for (int i = 0; i < 4; ++i) bfr[i] = *(const bf16x8*)&lAB[b_off[h][i]];
#pragma unroll
            for (int mi = 0; mi < 4; ++mi)
#pragma unroll
                for (int ni = 0; ni < 4; ++ni)
                    acc[mi][ni] = __builtin_amdgcn_mfma_f32_16x16x32_bf16(
                        af[mi], bfr[ni], acc[mi][ni], 0, 0, 0);
        }
        __syncthreads();
    }

    const bool isb_z = (tN >= 2048);
    u16* dst = isb_z ? Z : Xs;
#pragma unroll
    for (int mi = 0; mi < 4; ++mi) {
#pragma unroll
        for (int ni = 0; ni < 4; ++ni) {
            int col = tN + wc * 64 + ni * 16 + l16;
            float bv = bias[col];
            int ocol = isb_z ? (col - 2048) : col;
#pragma unroll
            for (int r = 0; r < 4; ++r) {
                int row = tM + wr * 64 + mi * 16 + quad * 4 + r;
                dst[(size_t)row * 2048 + ocol] = f2bf(acc[mi][ni][r] + bv);
            }
        }
    }
}

// ---------- kernel 3: cast8 — W_out->bf16 | W_dt->fp8 | W_B,W_C->bf16 | xsb->fp8 ----------
__global__ __launch_bounds__(256) void cast8_kernel(const float* __restrict__ W_out,
                                                    u16* __restrict__ wb_out,
                                                    const float* __restrict__ W_dt,
                                                    u8* __restrict__ w8,
                                                    const float* __restrict__ W_B,
                                                    const float* __restrict__ W_C,
                                                    u16* __restrict__ wbc,
                                                    const u16* __restrict__ xsb,
                                                    u8* __restrict__ xs8) {
    int j = blockIdx.x * 256 + threadIdx.x;
    if (j < 1048576) { cast4f(W_out, wb_out, j); return; }
    j -= 1048576;
    if (j < 1048576) {              // W_dt: float4 -> 4 fp8
        float4 f = ((const float4*)W_dt)[j];
        int p = __builtin_amdgcn_cvt_pk_fp8_f32(f.x, f.y, 0, false);
        p = __builtin_amdgcn_cvt_pk_fp8_f32(f.z, f.w, p, true);
        ((u32*)w8)[j] = p;
        return;
    }
    j -= 1048576;
    if (j < 16384) {                // W_B, W_C -> wbc rows 0..31 (bf16)
        if (j < 8192) cast4f(W_B, wbc, j);
        else          cast4f(W_C, wbc + (size_t)16 * 2048, j - 8192);
        return;
    }
    j -= 16384;
    if (j < 1048576) {              // xsb: 8 bf16 -> 8 fp8
        ushort4 h0 = ((const ushort4*)xsb)[2 * j];
        ushort4 h1 = ((const ushort4*)xsb)[2 * j + 1];
        int p0 = __builtin_amdgcn_cvt_pk_fp8_f32(b2f(h0.x), b2f(h0.y), 0, false);
        p0 = __builtin_amdgcn_cvt_pk_fp8_f32(b2f(h0.z), b2f(h0.w), p0, true);
        int p1 = __builtin_amdgcn_cvt_pk_fp8_f32(b2f(h1.x), b2f(h1.y), 0, false);
        p1 = __builtin_amdgcn_cvt_pk_fp8_f32(b2f(h1.z), b2f(h1.w), p1, true);
        ((u32*)xs8)[2 * j] = p0;
        ((u32*)xs8)[2 * j + 1] = p1;
    }
}

// ---------- kernel 4: dt GEMM, MX-fp8 (scale=1) + bf16 dots subtile ----------
// y<32: fp8, BM=128/BN=64, 128-byte K-tiles, 16 iters, mfma_scale 16x16x128
//       (2x bf16 rate). Same 24 KB / 6-DMA / XOR-swizzle geometry (rows=128B).
// y==32: bf16 dots: dots[t,0..31] = xs . [W_B;W_C] (raw, bias applied in ssm).
__global__ __launch_bounds__(256) void gemm_dtmx(const u8* __restrict__ xs8,
                                                 const u8* __restrict__ w8,
                                                 const u16* __restrict__ xsb,
                                                 const u16* __restrict__ wbc,
                                                 const float* __restrict__ bias,
                                                 u8* __restrict__ dt8,
                                                 u16* __restrict__ dots) {
    __shared__ __align__(16) u8 lds[24576];
    const int tid = threadIdx.x;
    const int wave = tid >> 6, lane = tid & 63;
    const int quad = lane >> 4, l16 = lane & 15;
    const int tM = blockIdx.x * 128;
    const int wr = wave >> 1, wc = wave & 1;
    const int rowin = tid >> 3;                 // 0..31

    if (blockIdx.y < 32) {
        // ---------------- fp8 MX path ----------------
        const int tN = blockIdx.y * 64;
        const int col16 = ((tid & 7) ^ (rowin & 7)) * 16;   // swizzled 16B chunk
        const u8* gptr[6];
        u8* ldst[6];
#pragma unroll
        for (int i = 0; i < 6; ++i) {
            int trow = i * 32 + rowin;
            const u8* src = (i < 4) ? (xs8 + (size_t)(tM + trow) * 2048)
                                    : (w8 + (size_t)(tN + (trow - 128)) * 2048);
            gptr[i] = src + col16;
            ldst[i] = &lds[(i * 32 + wave * 8) * 128];
        }
        // lane's A/B fragment: 32 bytes = chunks {quad*2, quad*2+1} of its row
        int a_off[4][2], b_off[2][2];
#pragma unroll
        for (int mi = 0; mi < 4; ++mi) {
            int row = wr * 64 + mi * 16 + l16;
            a_off[mi][0] = row * 128 + (((quad * 2)     ^ (row & 7)) << 4);
            a_off[mi][1] = row * 128 + (((quad * 2 + 1) ^ (row & 7)) << 4);
        }
#pragma unroll
        for (int ni = 0; ni < 2; ++ni) {
            int row = 128 + wc * 32 + ni * 16 + l16;
            b_off[ni][0] = row * 128 + (((quad * 2)     ^ (row & 7)) << 4);
            b_off[ni][1] = row * 128 + (((quad * 2 + 1) ^ (row & 7)) << 4);
        }

        f32x4 acc[4][2] = {};

        for (int kt = 0; kt < 2048; kt += 128) {
#pragma unroll
            for (int i = 0; i < 6; ++i) async16(gptr[i] + kt, ldst[i]);
            __syncthreads();
            i32x8 af[4], bf[2];
#pragma unroll
            for (int mi = 0; mi < 4; ++mi) {
                i32x4 p0 = *(const i32x4*)&lds[a_off[mi][0]];
                i32x4 p1 = *(const i32x4*)&lds[a_off[mi][1]];
#pragma unroll
                for (int j = 0; j < 4; ++j) { af[mi][j] = p0[j]; af[mi][j + 4] = p1[j]; }
            }
#pragma unroll
            for (int ni = 0; ni < 2; ++ni) {
                i32x4 p0 = *(const i32x4*)&lds[b_off[ni][0]];
                i32x4 p1 = *(const i32x4*)&lds[b_off[ni][1]];
#pragma unroll
                for (int j = 0; j < 4; ++j) { bf[ni][j] = p0[j]; bf[ni][j + 4] = p1[j]; }
            }
#pragma unroll
            for (int mi = 0; mi < 4; ++mi)
#pragma unroll
                for (int ni = 0; ni < 2; ++ni)
                    acc[mi][ni] = __builtin_amdgcn_mfma_scale_f32_16x16x128_f8f6f4(
                        af[mi], bf[ni], acc[mi][ni],
                        0, 0,            // cbsz = fp8, blgp = fp8
                        0, 0x7F,         // A scale: opsel 0, E8M0 127 = 1.0
                        0, 0x7F);        // B scale
            __syncthreads();
        }

#pragma unroll
        for (int mi = 0; mi < 4; ++mi) {
#pragma unroll
            for (int ni = 0; ni < 2; ++ni) {
                int col = tN + wc * 32 + ni * 16 + l16;
                float bv = bias[col];
#pragma unroll
                for (int r = 0; r < 4; ++r) {
                    int row = tM + wr * 64 + mi * 16 + quad * 4 + r;
                    float v = acc[mi][ni][r] + bv;
                    float sp = (v > 20.f) ? v : log1pf(__expf(v));
                    sp = fminf(sp, 1.0f);
                    int p = __builtin_amdgcn_cvt_pk_fp8_f32(sp, sp, 0, false);
                    dt8[(size_t)row * 2048 + col] = (u8)(p & 0xFF);
                }
            }
        }
    } else {
        // ---------------- bf16 dots subtile ----------------
        u16* lds16 = (u16*)lds;
        const int col8 = ((tid & 7) ^ (rowin & 7)) * 8;
        const u16* gptr[6];
        u16* ldst[6];
#pragma unroll
        for (int i = 0; i < 6; ++i) {
            int trow = i * 32 + rowin;
            const u16* src = (i < 4) ? (xsb + (size_t)(tM + trow) * 2048)
                                     : (wbc + (size_t)(trow - 128) * 2048);
            gptr[i] = src + col8;
            ldst[i] = &lds16[(i * 32 + wave * 8) * 64];
        }
        int a_off[2][4], b_off[2][2];
#pragma unroll
        for (int h = 0; h < 2; ++h) {
#pragma unroll
            for (int mi = 0; mi < 4; ++mi)
                a_off[h][mi] = (wr * 64 + mi * 16 + l16) * 64 +
                               (((h * 4 + quad) ^ (l16 & 7)) * 8);
#pragma unroll
            for (int ni = 0; ni < 2; ++ni)
                b_off[h][ni] = (128 + wc * 32 + ni * 16 + l16) * 64 +
                               (((h * 4 + quad) ^ (l16 & 7)) * 8);
        }

        f32x4 acc[4][2] = {};

        for (int kt = 0; kt < 2048; kt += 64) {
#pragma unroll
            for (int i = 0; i < 6; ++i) async16(gptr[i] + kt, ldst[i]);
            __syncthreads();
            bf16x8 af[2][4], bfr[2][2];
#pragma unroll
            for (int h = 0; h < 2; ++h) {
#pragma unroll
                for (int mi = 0; mi < 4; ++mi) af[h][mi] = *(const bf16x8*)&lds16[a_off[h][mi]];
#pragma unroll
                for (int ni = 0; ni < 2; ++ni) bfr[h][ni] = *(const bf16x8*)&lds16[b_off[h][ni]];
            }
#pragma unroll
            for (int h = 0; h < 2; ++h)
#pragma unroll
                for (int mi = 0; mi < 4; ++mi)
#pragma unroll
                    for (int ni = 0; ni < 2; ++ni)
                        acc[mi][ni] = __builtin_amdgcn_mfma_f32_16x16x32_bf16(
                            af[h][mi], bfr[h][ni], acc[mi][ni], 0, 0, 0);
            __syncthreads();
        }

#pragma unroll
        for (int mi = 0; mi < 4; ++mi) {
#pragma unroll
            for (int ni = 0; ni < 2; ++ni) {
                int nc = wc * 32 + ni * 16 + l16;
                if (nc < 32) {
#pragma unroll
                    for (int r = 0; r < 4; ++r) {
                        int row = tM + wr * 64 + mi * 16 + quad * 4 + r;
                        dots[(size_t)row * 32 + nc] = f2bf(acc[mi][ni][r]);
                    }
                }
            }
        }
    }
}

// ---------- kernel 5: fused P + SSM + gate (fp8 dt; round-8-proven numerics) ----------
__global__ __launch_bounds__(256) void ssm_gate_kernel(const u8* __restrict__ dt8,
                                                       const u16* __restrict__ xsb,
                                                       const u16* __restrict__ zb,
                                                       const float* __restrict__ A,
                                                       const u16* __restrict__ dots,
                                                       const float* __restrict__ bB,
                                                       const float* __restrict__ bC,
                                                       u16* __restrict__ gated) {
    __shared__ float Pl[16];
    int t = blockIdx.x, tid = threadIdx.x;
    if (tid < 16) {
        float Bv = b2f(dots[(size_t)t * 32 + tid]) + bB[tid];
        float Cv = b2f(dots[(size_t)t * 32 + 16 + tid]) + bC[tid];
        Pl[tid] = Bv * Cv;
    }
    __syncthreads();
    size_t dbase = (size_t)t * DIM;
    int d0 = tid * 8;
    unsigned long long dl = *(const unsigned long long*)(dt8 + dbase + d0);
    unsigned dlo = (unsigned)dl, dhi = (unsigned)(dl >> 32);
    ushort4 xsh[2], zh[2];
    xsh[0] = *(const ushort4*)(xsb + dbase + d0);
    xsh[1] = *(const ushort4*)(xsb + dbase + d0 + 4);
    zh[0]  = *(const ushort4*)(zb + dbase + d0);
    zh[1]  = *(const ushort4*)(zb + dbase + d0 + 4);
    float dtv[8], xsv[8], zv[8];
    dtv[0] = __builtin_amdgcn_cvt_f32_fp8(dlo, 0);
    dtv[1] = __builtin_amdgcn_cvt_f32_fp8(dlo, 1);
    dtv[2] = __builtin_amdgcn_cvt_f32_fp8(dlo, 2);
    dtv[3] = __builtin_amdgcn_cvt_f32_fp8(dlo, 3);
    dtv[4] = __builtin_amdgcn_cvt_f32_fp8(dhi, 0);
    dtv[5] = __builtin_amdgcn_cvt_f32_fp8(dhi, 1);
    dtv[6] = __builtin_amdgcn_cvt_f32_fp8(dhi, 2);
    dtv[7] = __builtin_amdgcn_cvt_f32_fp8(dhi, 3);
#pragma unroll
    for (int h = 0; h < 2; ++h) {
        const u16* xp = (const u16*)&xsh[h];
        const u16* zp = (const u16*)&zh[h];
#pragma unroll
        for (int j = 0; j < 4; ++j) {
            xsv[h * 4 + j] = b2f(xp[j]);
            zv[h * 4 + j]  = b2f(zp[j]);
        }
    }
    float s[8] = {};
#pragma unroll
    for (int n = 0; n < 16; ++n) {
        float4 a0 = *(const float4*)(A + n * DIM + d0);
        float4 a1 = *(const float4*)(A + n * DIM + d0 + 4);
        float pn = Pl[n];
        float av[8] = {a0.x, a0.y, a0.z, a0.w, a1.x, a1.y, a1.z, a1.w};
#pragma unroll
        for (int j = 0; j < 8; ++j) s[j] += pn * __expf(av[j] * dtv[j]);
    }
    ushort4 r0, r1;
    u16* rp0 = (u16*)&r0; u16* rp1 = (u16*)&r1;
#pragma unroll
    for (int j = 0; j < 8; ++j) {
        float y = s[j] * xsv[j];
        float sz = zv[j] * (1.0f / (1.0f + __expf(-zv[j])));
        u16 hv = f2bf(y * sz);
        if (j < 4) rp0[j] = hv; else rp1[j - 4] = hv;
    }
    *(ushort4*)(gated + dbase + d0) = r0;
    *(ushort4*)(gated + dbase + d0 + 4) = r1;
}

// ---------- kernel 6: out GEMM bf16 narrow (round-6/7 proven) ----------
__global__ __launch_bounds__(256) void gemm_out(const u16* __restrict__ A,
                                                const u16* __restrict__ W,
                                                const float* __restrict__ bias,
                                                const float* __restrict__ resid,
                                                float* __restrict__ C) {
    __shared__ __align__(16) u16 lAB[192 * 64];  // 24 KB
    const int tid = threadIdx.x;
    const int wave = tid >> 6, lane = tid & 63;
    const int quad = lane >> 4, l16 = lane & 15;
    const int tM = blockIdx.x * 128;
    const int tN = blockIdx.y * 64;
    const int wr = wave >> 1, wc = wave & 1;

    const int rowin = tid >> 3;
    const int col8 = ((tid & 7) ^ (rowin & 7)) * 8;
    const u16* gptr[6];
    u16* ldst[6];
#pragma unroll
    for (int i = 0; i < 6; ++i) {
        int trow = i * 32 + rowin;
        const u16* src = (i < 4) ? (A + (size_t)(tM + trow) * 2048)
                                 : (W + (size_t)(tN + (trow - 128)) * 2048);
        gptr[i] = src + col8;
        ldst[i] = &lAB[(i * 32 + wave * 8) * 64];
    }

    int a_off[2][4], b_off[2][2];
#pragma unroll
    for (int h = 0; h < 2; ++h) {
#pragma unroll
        for (int mi = 0; mi < 4; ++mi)
            a_off[h][mi] = (wr * 64 + mi * 16 + l16) * 64 +
                           (((h * 4 + quad) ^ (l16 & 7)) * 8);
#pragma unroll
        for (int ni = 0; ni < 2; ++ni)
            b_off[h][ni] = (128 + wc * 32 + ni * 16 + l16) * 64 +
                           (((h * 4 + quad) ^ (l16 & 7)) * 8);
    }

    f32x4 acc[4][2] = {};

    for (int kt = 0; kt < 2048; kt += 64) {
#pragma unroll
        for (int i = 0; i < 6; ++i) async16(gptr[i] + kt, ldst[i]);
        __syncthreads();
        bf16x8 af[2][4], bfr[2][2];
#pragma unroll
        for (int h = 0; h < 2; ++h) {
#pragma unroll
            for (int mi = 0; mi < 4; ++mi) af[h][mi] = *(const bf16x8*)&lAB[a_off[h][mi]];
#pragma unroll
            for (int ni = 0; ni < 2; ++ni) bfr[h][ni] = *(const bf16x8*)&lAB[b_off[h][ni]];
        }
#pragma unroll
        for (int h = 0; h < 2; ++h)
#pragma unroll
            for (int mi = 0; mi < 4; ++mi)
#pragma unroll
                for (int ni = 0; ni < 2; ++ni)
                    acc[mi][ni] = __builtin_amdgcn_mfma_f32_16x16x32_bf16(
                        af[h][mi], bfr[h][ni], acc[mi][ni], 0, 0, 0);
        __syncthreads();
    }

#pragma unroll
    for (int mi = 0; mi < 4; ++mi) {
#pragma unroll
        for (int ni = 0; ni < 2; ++ni) {
            int col = tN + wc * 32 + ni * 16 + l16;
            float bv = bias[col];
#pragma unroll
            for (int r = 0; r < 4; ++r) {
                int row = tM + wr * 64 + mi * 16 + quad * 4 + r;
                size_t idx = (size_t)row * 2048 + col;
                C[idx] = acc[mi][ni][r] + bv + resid[idx];
            }
        }
    }
}

// ---------- launch ----------
// Aliased ws layout, 84.15 MB peak (= proven rounds 1-7 budget):
//   [0, 16.78M):       wb_in (castln->wide); after wide: wb_out [0,8.39M) +
//                      w8_dt fp8 [8.39M,12.58M) + wbc bf16 64x2048 [12.58M,12.85M)
//   [16.78M, 33.55M):  xnb (castln->wide) -> gated (ssm->out)
//   [33.55M, 50.33M):  xsb bf16
//   [50.33M, 67.11M):  zb bf16
//   [67.11M, 75.50M):  dt8 fp8
//   [75.50M, 83.89M):  xs8 fp8
//   [83.89M, 84.15M):  dots bf16 (T x 32)
extern "C" void kernel_launch(void* const* d_in, const int* in_sizes, int n_in,
                              void* d_out, int out_size, void* d_ws, size_t ws_size,
                              hipStream_t stream) {
    const float* x      = (const float*)d_in[0];
    const float* ln_g   = (const float*)d_in[1];
    const float* ln_b   = (const float*)d_in[2];
    const float* W_in   = (const float*)d_in[3];
    const float* b_in   = (const float*)d_in[4];
    const float* stateA = (const float*)d_in[5];
    const float* W_B    = (const float*)d_in[6];
    const float* b_B    = (const float*)d_in[7];
    const float* W_C    = (const float*)d_in[8];
    const float* b_C    = (const float*)d_in[9];
    const float* W_dt   = (const float*)d_in[10];
    const float* b_dt   = (const float*)d_in[11];
    const float* W_out  = (const float*)d_in[12];
    const float* b_out  = (const float*)d_in[13];

    char* ws = (char*)d_ws;
    u16*   wb_in  = (u16*)(ws);                     // castln -> wide
    u16*   wb_out = (u16*)(ws);                     // cast8 -> out
    u8*    w8_dt  = (u8*)(ws + 8388608);            // cast8 -> dtmx
    u16*   wbc    = (u16*)(ws + 12582912);          // cast8 -> dtmx (dots tile)
    u16*   xnb    = (u16*)(ws + 16777216);          // castln -> wide
    u16*   gated  = (u16*)(ws + 16777216);          // ssm -> out
    u16*   xsb    = (u16*)(ws + 33554432);
    u16*   zb     = (u16*)(ws + 50331648);
    u8*    dt8    = (u8*)(ws + 67108864);
    u8*    xs8    = (u8*)(ws + 75497472);
    u16*   dotsb  = (u16*)(ws + 83886080);

    // 1. W_in cast + LN(x)
    castln_kernel<<<12288, 256, 0, stream>>>(W_in, wb_in, x, ln_g, ln_b, xnb);
    // 2. xz = xn @ W_in^T + b_in, split into xsb | zb
    gemm_wide<<<dim3(32, 32), 256, 0, stream>>>(xnb, wb_in, b_in, xsb, zb, 2048);
    // 3. casts (wb_in/xnb dead): W_out->bf16, W_dt->fp8, W_B/W_C->bf16, xsb->fp8
    cast8_kernel<<<12352, 256, 0, stream>>>(W_out, wb_out, W_dt, w8_dt,
                                            W_B, W_C, wbc, xsb, xs8);
    // 4. dt = min(softplus(xs @ W_dt^T + b_dt),1) -> fp8 (MX 2x rate) + BC dots (bf16)
    gemm_dtmx<<<dim3(32, 33), 256, 0, stream>>>(xs8, w8_dt, xsb, wbc, b_dt,
                                                dt8, dotsb);
    // 5. fused P + SSM + gate (gated overwrites xnb slot)
    ssm_gate_kernel<<<T_TOK, 256, 0, stream>>>(dt8, xsb, zb, stateA, dotsb,
                                               b_B, b_C, gated);
    // 6. out = gated @ W_out^T + b_out + x
    gemm_out<<<dim3(32, 32), 256, 0, stream>>>(gated, wb_out, b_out, x,
                                               (float*)d_out);
}